// Round 3
// baseline (239.801 us; speedup 1.0000x reference)
//
#include <hip/hip_runtime.h>

typedef __bf16 bf16x8 __attribute__((ext_vector_type(8)));
typedef float f32x16 __attribute__((ext_vector_type(16)));

#define B_  4096   // batch
#define IN_ 1024
#define H_  1024
#define KD  2048   // IN_ + H_
#define ND  4096   // 4 * H_ (gates interleaved: row n = 4*h + g)

__device__ __forceinline__ unsigned short f2bf(float f) {
    union { float f; unsigned u; } v; v.f = f;
    unsigned r = v.u + 0x7FFFu + ((v.u >> 16) & 1u);   // RNE
    return (unsigned short)(r >> 16);
}

// ------- pack Z = [incoming|old_h] -> bf16 [B_,KD]  and
//         pack V -> bf16 [ND,KD] with rows interleaved n = 4*h + g,
//         in ONE kernel (grid: first 8192 blocks Z, next 8192 blocks V) -------
__global__ __launch_bounds__(256) void pack_all(const float* __restrict__ x,
                                                const float* __restrict__ h,
                                                const float* __restrict__ wi, const float* __restrict__ ui,
                                                const float* __restrict__ wo, const float* __restrict__ uo,
                                                const float* __restrict__ wf, const float* __restrict__ uf,
                                                const float* __restrict__ wc, const float* __restrict__ uc,
                                                unsigned short* __restrict__ Z,
                                                unsigned short* __restrict__ V) {
    const int bid = blockIdx.x;
    const float* src;
    unsigned short* dst;
    if (bid < 8192) {
        int idx = (bid * 256 + threadIdx.x) * 4;
        int m = idx >> 11;
        int k = idx & (KD - 1);
        src = (k < IN_) ? (x + (size_t)m * IN_ + k)
                        : (h + (size_t)m * H_ + (k - IN_));
        dst = Z + idx;
    } else {
        int idx = ((bid - 8192) * 256 + threadIdx.x) * 4;
        int n = idx >> 11;          // interleaved row
        int k = idx & (KD - 1);
        int g = n & 3;              // gate 0..3 = i,o,f,c
        int r = n >> 2;             // h index
        const float* wg = (g == 0) ? wi : (g == 1) ? wo : (g == 2) ? wf : wc;
        const float* ug = (g == 0) ? ui : (g == 1) ? uo : (g == 2) ? uf : uc;
        src = (k < IN_) ? (wg + (size_t)r * IN_ + k)
                        : (ug + (size_t)r * H_ + (k - IN_));
        dst = V + idx;
    }
    float4 v = *(const float4*)src;
    ushort4 o;
    o.x = f2bf(v.x); o.y = f2bf(v.y); o.z = f2bf(v.z); o.w = f2bf(v.w);
    *(ushort4*)dst = o;
}

// ------- fused GEMM + LSTM: gates = Z @ V^T (+b), then elementwise cell ------
// 128x128 tile, BK=64, 4 waves (2x2) of 64x64, mfma_f32_32x32x16_bf16,
// global_load_lds width=16 staging, XOR-swizzled LDS (0 bank conflicts).
__global__ __launch_bounds__(256) void gemm_lstm(const unsigned short* __restrict__ Z,
                                                 const unsigned short* __restrict__ V,
                                                 const float* __restrict__ oc,
                                                 const float* __restrict__ bi,
                                                 const float* __restrict__ bo,
                                                 const float* __restrict__ bff,
                                                 const float* __restrict__ bc,
                                                 float* __restrict__ nh,
                                                 float* __restrict__ nc) {
    __shared__ unsigned short lA[128 * 64];
    __shared__ unsigned short lB[128 * 64];
    const int tid  = threadIdx.x;
    const int lane = tid & 63;
    const int w    = tid >> 6;
    const int wr   = w >> 1;
    const int wc   = w & 1;
    const int m0   = blockIdx.y * 128;
    const int n0   = blockIdx.x * 128;

    f32x16 acc[2][2];
#pragma unroll
    for (int i = 0; i < 2; ++i)
#pragma unroll
        for (int j = 0; j < 2; ++j)
#pragma unroll
            for (int v = 0; v < 16; ++v) acc[i][j][v] = 0.f;

    // staging: 16 chunks of 1 KiB per tile; wave w owns chunks w*4 .. w*4+3.
    // chunk c covers tile rows [(w*4+c)*8, +8), all 64 cols.
    // XOR swizzle: col-block cb of row r lands at slot (cb ^ (r&7)).
    // global_load_lds dest = base + lane*16, so lane l (row lr=l>>3, dest
    // slot l&7) fetches global col-block (l&7) ^ lr.
    const int lr = lane >> 3;
    const int lc = ((lane & 7) ^ lr) * 8;
    const unsigned short* gA = Z + (size_t)(m0 + w * 32 + lr) * KD + lc;
    const unsigned short* gB = V + (size_t)(n0 + w * 32 + lr) * KD + lc;
    unsigned short* lAw = lA + w * 32 * 64;
    unsigned short* lBw = lB + w * 32 * 64;

    const int l31 = lane & 31;
    const int e   = lane >> 5;        // k-half selector
    const int sw7 = lane & 7;         // row&7 for swizzle on the read side

    for (int k0 = 0; k0 < KD; k0 += 64) {
#pragma unroll
        for (int c = 0; c < 4; ++c) {
            __builtin_amdgcn_global_load_lds(
                (const __attribute__((address_space(1))) void*)(gA + (size_t)c * 8 * KD + k0),
                (__attribute__((address_space(3))) void*)(lAw + c * 512), 16, 0, 0);
            __builtin_amdgcn_global_load_lds(
                (const __attribute__((address_space(1))) void*)(gB + (size_t)c * 8 * KD + k0),
                (__attribute__((address_space(3))) void*)(lBw + c * 512), 16, 0, 0);
        }
        __syncthreads();
#pragma unroll
        for (int ks = 0; ks < 4; ++ks) {            // K=16 per step
            bf16x8 af[2], bfr[2];
            const int cb = ks * 2 + e;              // col-block 0..7
            const int sw = (cb ^ sw7) * 8;          // swizzled short-offset
#pragma unroll
            for (int i = 0; i < 2; ++i) {
                af[i]  = *(const bf16x8*)(lA + (wr * 64 + i * 32 + l31) * 64 + sw);
                bfr[i] = *(const bf16x8*)(lB + (wc * 64 + i * 32 + l31) * 64 + sw);
            }
#pragma unroll
            for (int mi = 0; mi < 2; ++mi)
#pragma unroll
                for (int ni = 0; ni < 2; ++ni)
                    acc[mi][ni] = __builtin_amdgcn_mfma_f32_32x32x16_bf16(
                        af[mi], bfr[ni], acc[mi][ni], 0, 0, 0);
        }
        __syncthreads();
    }

    // -------- fused LSTM epilogue --------
    // C/D (32x32): col = n0+wc*64+ni*32+(lane&31), row = m0+wr*64+mi*32
    //              + (reg&3) + 8*(reg>>2) + 4*(lane>>5).
    // col = 4h+g with g = lane&3, h = bx*32 + wc*16 + ni*8 + ((lane>>2)&7).
    // XOR-gather: round t, lane sends acc[..][4q + ((g^t)&3)]; shfl_xor(t)
    // delivers gate (g^t) of row (.. + 8q + g + 4e) to this lane.
    const int g  = lane & 3;
    const int hb = (lane >> 2) & 7;
    const int h0 = blockIdx.x * 32 + wc * 16;
    const int rowb = m0 + wr * 64 + g + 4 * e;

#pragma unroll
    for (int ni = 0; ni < 2; ++ni) {
        const int h = h0 + ni * 8 + hb;
        const float vbi = bi[h];
        const float vbo = bo[h];
        const float vbf = bff[h];
        const float vbc = bc[h];
#pragma unroll
        for (int mi = 0; mi < 2; ++mi)
#pragma unroll
            for (int q = 0; q < 4; ++q) {
                float recv[4];
#pragma unroll
                for (int t = 0; t < 4; ++t) {
                    float x = acc[mi][ni][4 * q + ((g ^ t) & 3)];
                    recv[t] = __shfl_xor(x, t, 64);
                }
                float gi = recv[g] + vbi;
                float go = recv[g ^ 1] + vbo;
                float gf = recv[g ^ 2] + vbf;
                float gc = recv[g ^ 3] + vbc;
                const int row = rowb + mi * 32 + 8 * q;
                const size_t off = (size_t)row * H_ + h;
                float iv = 1.f / (1.f + __expf(-gi));
                float ov = 1.f / (1.f + __expf(-go));
                float fv = 1.f / (1.f + __expf(-gf));
                float ct = 1.f - 2.f / (__expf(2.f * gc) + 1.f);
                float cv = fv * oc[off] + iv * ct;
                float th = 1.f - 2.f / (__expf(2.f * cv) + 1.f);
                nc[off] = cv;
                nh[off] = ov * th;
            }
    }
}

extern "C" void kernel_launch(void* const* d_in, const int* in_sizes, int n_in,
                              void* d_out, int out_size, void* d_ws, size_t ws_size,
                              hipStream_t stream) {
    const float* incoming = (const float*)d_in[0];
    const float* old_h    = (const float*)d_in[1];
    const float* old_c    = (const float*)d_in[2];
    const float* w_i = (const float*)d_in[3];
    const float* b_i = (const float*)d_in[4];
    const float* u_i = (const float*)d_in[5];
    const float* w_o = (const float*)d_in[6];
    const float* b_o = (const float*)d_in[7];
    const float* u_o = (const float*)d_in[8];
    const float* w_f = (const float*)d_in[9];
    const float* b_f = (const float*)d_in[10];
    const float* u_f = (const float*)d_in[11];
    const float* w_c = (const float*)d_in[12];
    const float* b_c = (const float*)d_in[13];
    const float* u_c = (const float*)d_in[14];

    unsigned short* Z = (unsigned short*)d_ws;                 // 16 MiB
    unsigned short* V = Z + (size_t)B_ * KD;                   // 16 MiB

    pack_all<<<16384, 256, 0, stream>>>(incoming, old_h,
                                        w_i, u_i, w_o, u_o, w_f, u_f, w_c, u_c,
                                        Z, V);
    gemm_lstm<<<dim3(ND / 128, B_ / 128), 256, 0, stream>>>(
        Z, V, old_c, b_i, b_o, b_f, b_c,
        (float*)d_out, (float*)d_out + (size_t)B_ * H_);
}

// Round 4
// 218.314 us; speedup vs baseline: 1.0984x; 1.0984x over previous
//
#include <hip/hip_runtime.h>

typedef __bf16 bf16x8 __attribute__((ext_vector_type(8)));
typedef float f32x4 __attribute__((ext_vector_type(4)));

#define B_  4096   // batch
#define IN_ 1024
#define H_  1024
#define KD  2048   // IN_ + H_
#define ND  4096   // 4 * H_ (gates interleaved: row n = 4*h + g)

__device__ __forceinline__ unsigned short f2bf(float f) {
    union { float f; unsigned u; } v; v.f = f;
    unsigned r = v.u + 0x7FFFu + ((v.u >> 16) & 1u);   // RNE
    return (unsigned short)(r >> 16);
}

// ------- pack Z = [incoming|old_h] -> bf16 [B_,KD]  and
//         pack V -> bf16 [ND,KD] with rows interleaved n = 4*h + g,
//         in ONE kernel (grid: first 8192 blocks Z, next 8192 blocks V) -------
__global__ __launch_bounds__(256) void pack_all(const float* __restrict__ x,
                                                const float* __restrict__ h,
                                                const float* __restrict__ wi, const float* __restrict__ ui,
                                                const float* __restrict__ wo, const float* __restrict__ uo,
                                                const float* __restrict__ wf, const float* __restrict__ uf,
                                                const float* __restrict__ wc, const float* __restrict__ uc,
                                                unsigned short* __restrict__ Z,
                                                unsigned short* __restrict__ V) {
    const int bid = blockIdx.x;
    const float* src;
    unsigned short* dst;
    if (bid < 8192) {
        int idx = (bid * 256 + threadIdx.x) * 4;
        int m = idx >> 11;
        int k = idx & (KD - 1);
        src = (k < IN_) ? (x + (size_t)m * IN_ + k)
                        : (h + (size_t)m * H_ + (k - IN_));
        dst = Z + idx;
    } else {
        int idx = ((bid - 8192) * 256 + threadIdx.x) * 4;
        int n = idx >> 11;          // interleaved row
        int k = idx & (KD - 1);
        int g = n & 3;              // gate 0..3 = i,o,f,c
        int r = n >> 2;             // h index
        const float* wg = (g == 0) ? wi : (g == 1) ? wo : (g == 2) ? wf : wc;
        const float* ug = (g == 0) ? ui : (g == 1) ? uo : (g == 2) ? uf : uc;
        src = (k < IN_) ? (wg + (size_t)r * IN_ + k)
                        : (ug + (size_t)r * H_ + (k - IN_));
        dst = V + idx;
    }
    float4 v = *(const float4*)src;
    ushort4 o;
    o.x = f2bf(v.x); o.y = f2bf(v.y); o.z = f2bf(v.z); o.w = f2bf(v.w);
    *(ushort4*)dst = o;
}

// ------- fused GEMM + LSTM: gates = Z @ V^T (+b), then elementwise cell ------
// 128x128 tile, BK=64, 4 waves (2x2) of 64x64, mfma_f32_16x16x32_bf16,
// global_load_lds width=16 staging, XOR-swizzled LDS (verified 0 conflicts).
// NOTE: 16x16x32 (not 32x32x16) is required for zero LDS conflicts: each
// 16-lane quarter reads a DIFFERENT col-block (cb depends on lane>>4), so
// same-bank aliasing is 2-way max (free). 32x32 forces 32 rows @ same cb ->
// structural 4-way alias (row stride = 128 B = bank period) -> +4 cyc/read.
__global__ __launch_bounds__(256) void gemm_lstm(const unsigned short* __restrict__ Z,
                                                 const unsigned short* __restrict__ V,
                                                 const float* __restrict__ oc,
                                                 const float* __restrict__ bi,
                                                 const float* __restrict__ bo,
                                                 const float* __restrict__ bff,
                                                 const float* __restrict__ bc,
                                                 float* __restrict__ nh,
                                                 float* __restrict__ nc) {
    __shared__ unsigned short lA[128 * 64];
    __shared__ unsigned short lB[128 * 64];
    const int tid  = threadIdx.x;
    const int lane = tid & 63;
    const int w    = tid >> 6;
    const int wr   = w >> 1;
    const int wc   = w & 1;
    const int m0   = blockIdx.y * 128;
    const int n0   = blockIdx.x * 128;

    f32x4 acc[4][4];
#pragma unroll
    for (int i = 0; i < 4; ++i)
#pragma unroll
        for (int j = 0; j < 4; ++j) acc[i][j] = (f32x4){0.f, 0.f, 0.f, 0.f};

    // staging: 16 chunks of 1 KiB per tile; wave w owns chunks w*4 .. w*4+3.
    // chunk c covers tile rows [(w*4+c)*8, +8), all 64 cols.
    // XOR swizzle: col-block cb of row r lands at slot (cb ^ (r&7)).
    // global_load_lds dest = base + lane*16, so lane l (row lr=l>>3, dest
    // slot l&7) fetches global col-block (l&7) ^ lr.
    const int lr = lane >> 3;
    const int lc = ((lane & 7) ^ lr) * 8;
    const unsigned short* gA = Z + (size_t)(m0 + w * 32 + lr) * KD + lc;
    const unsigned short* gB = V + (size_t)(n0 + w * 32 + lr) * KD + lc;
    unsigned short* lAw = lA + w * 32 * 64;
    unsigned short* lBw = lB + w * 32 * 64;

    const int lm = lane & 15;

    for (int k0 = 0; k0 < KD; k0 += 64) {
#pragma unroll
        for (int c = 0; c < 4; ++c) {
            __builtin_amdgcn_global_load_lds(
                (const __attribute__((address_space(1))) void*)(gA + (size_t)c * 8 * KD + k0),
                (__attribute__((address_space(3))) void*)(lAw + c * 512), 16, 0, 0);
            __builtin_amdgcn_global_load_lds(
                (const __attribute__((address_space(1))) void*)(gB + (size_t)c * 8 * KD + k0),
                (__attribute__((address_space(3))) void*)(lBw + c * 512), 16, 0, 0);
        }
        __syncthreads();
#pragma unroll
        for (int ks = 0; ks < 2; ++ks) {
            bf16x8 af[4], bf[4];
            const int cb = ks * 4 + (lane >> 4);   // col-block 0..7 within row
            const int sw = (cb ^ (lm & 7)) * 8;    // swizzled short-offset
#pragma unroll
            for (int i = 0; i < 4; ++i) {
                af[i] = *(const bf16x8*)(lA + (wr * 64 + i * 16 + lm) * 64 + sw);
                bf[i] = *(const bf16x8*)(lB + (wc * 64 + i * 16 + lm) * 64 + sw);
            }
#pragma unroll
            for (int mi = 0; mi < 4; ++mi)
#pragma unroll
                for (int ni = 0; ni < 4; ++ni)
                    acc[mi][ni] = __builtin_amdgcn_mfma_f32_16x16x32_bf16(
                        af[mi], bf[ni], acc[mi][ni], 0, 0, 0);
        }
        __syncthreads();
    }

    // -------- fused LSTM epilogue --------
    // acc element: row = m0+wr*64+mi*16+4a+v, col = n0+wc*64+ni*16+4b+g,
    // where a=lane>>4, b=(lane>>2)&3, g=lane&3; col = 4*h + gate.
    // XOR-shuffle gather: round t, every lane sends acc[..][(g^t)&3];
    // shfl_xor(t) delivers gate (g^t) of row (..+4a+g) to this lane.
    const int a  = lane >> 4;
    const int b  = (lane >> 2) & 3;
    const int g  = lane & 3;
    const int h0 = blockIdx.x * 32 + wc * 16;
    const int rowb = m0 + wr * 64 + 4 * a + g;

#pragma unroll
    for (int ni = 0; ni < 4; ++ni) {
        const int h = h0 + ni * 4 + b;
        const float vbi = bi[h];
        const float vbo = bo[h];
        const float vbf = bff[h];
        const float vbc = bc[h];
        // prefetch old_c for all 4 mi so the loads overlap the shuffle chain
        size_t offs[4];
        float ocp[4];
#pragma unroll
        for (int mi = 0; mi < 4; ++mi) {
            offs[mi] = (size_t)(rowb + mi * 16) * H_ + h;
            ocp[mi] = oc[offs[mi]];
        }
#pragma unroll
        for (int mi = 0; mi < 4; ++mi) {
            float recv[4];
#pragma unroll
            for (int t = 0; t < 4; ++t) {
                float x = acc[mi][ni][(g ^ t) & 3];
                recv[t] = __shfl_xor(x, t, 64);
            }
            float gi = recv[g] + vbi;
            float go = recv[g ^ 1] + vbo;
            float gf = recv[g ^ 2] + vbf;
            float gc = recv[g ^ 3] + vbc;
            float iv = 1.f / (1.f + __expf(-gi));
            float ov = 1.f / (1.f + __expf(-go));
            float fv = 1.f / (1.f + __expf(-gf));
            float ct = 1.f - 2.f / (__expf(2.f * gc) + 1.f);
            float cv = fv * ocp[mi] + iv * ct;
            float th = 1.f - 2.f / (__expf(2.f * cv) + 1.f);
            nc[offs[mi]] = cv;
            nh[offs[mi]] = ov * th;
        }
    }
}

extern "C" void kernel_launch(void* const* d_in, const int* in_sizes, int n_in,
                              void* d_out, int out_size, void* d_ws, size_t ws_size,
                              hipStream_t stream) {
    const float* incoming = (const float*)d_in[0];
    const float* old_h    = (const float*)d_in[1];
    const float* old_c    = (const float*)d_in[2];
    const float* w_i = (const float*)d_in[3];
    const float* b_i = (const float*)d_in[4];
    const float* u_i = (const float*)d_in[5];
    const float* w_o = (const float*)d_in[6];
    const float* b_o = (const float*)d_in[7];
    const float* u_o = (const float*)d_in[8];
    const float* w_f = (const float*)d_in[9];
    const float* b_f = (const float*)d_in[10];
    const float* u_f = (const float*)d_in[11];
    const float* w_c = (const float*)d_in[12];
    const float* b_c = (const float*)d_in[13];
    const float* u_c = (const float*)d_in[14];

    unsigned short* Z = (unsigned short*)d_ws;                 // 16 MiB
    unsigned short* V = Z + (size_t)B_ * KD;                   // 16 MiB

    pack_all<<<16384, 256, 0, stream>>>(incoming, old_h,
                                        w_i, u_i, w_o, u_o, w_f, u_f, w_c, u_c,
                                        Z, V);
    gemm_lstm<<<dim3(ND / 128, B_ / 128), 256, 0, stream>>>(
        Z, V, old_c, b_i, b_o, b_f, b_c,
        (float*)d_out, (float*)d_out + (size_t)B_ * H_);
}

// Round 5
// 211.359 us; speedup vs baseline: 1.1346x; 1.0329x over previous
//
#include <hip/hip_runtime.h>

typedef __bf16 bf16x8 __attribute__((ext_vector_type(8)));
typedef float f32x4 __attribute__((ext_vector_type(4)));

#define B_  4096   // batch
#define IN_ 1024
#define H_  1024
#define KD  2048   // IN_ + H_
#define ND  4096   // 4 * H_ (gates interleaved: row n = 4*h + g)

__device__ __forceinline__ unsigned short f2bf(float f) {
    union { float f; unsigned u; } v; v.f = f;
    unsigned r = v.u + 0x7FFFu + ((v.u >> 16) & 1u);   // RNE
    return (unsigned short)(r >> 16);
}

// ------- pack Z = [incoming|old_h] -> bf16 [B_,KD]  and
//         pack V -> bf16 [ND,KD] with rows interleaved n = 4*h + g ------------
__global__ __launch_bounds__(256) void pack_all(const float* __restrict__ x,
                                                const float* __restrict__ h,
                                                const float* __restrict__ wi, const float* __restrict__ ui,
                                                const float* __restrict__ wo, const float* __restrict__ uo,
                                                const float* __restrict__ wf, const float* __restrict__ uf,
                                                const float* __restrict__ wc, const float* __restrict__ uc,
                                                unsigned short* __restrict__ Z,
                                                unsigned short* __restrict__ V) {
    const int bid = blockIdx.x;
    const float* src;
    unsigned short* dst;
    if (bid < 8192) {
        int idx = (bid * 256 + threadIdx.x) * 4;
        int m = idx >> 11;
        int k = idx & (KD - 1);
        src = (k < IN_) ? (x + (size_t)m * IN_ + k)
                        : (h + (size_t)m * H_ + (k - IN_));
        dst = Z + idx;
    } else {
        int idx = ((bid - 8192) * 256 + threadIdx.x) * 4;
        int n = idx >> 11;          // interleaved row
        int k = idx & (KD - 1);
        int g = n & 3;              // gate 0..3 = i,o,f,c
        int r = n >> 2;             // h index
        const float* wg = (g == 0) ? wi : (g == 1) ? wo : (g == 2) ? wf : wc;
        const float* ug = (g == 0) ? ui : (g == 1) ? uo : (g == 2) ? uf : uc;
        src = (k < IN_) ? (wg + (size_t)r * IN_ + k)
                        : (ug + (size_t)r * H_ + (k - IN_));
        dst = V + idx;
    }
    float4 v = *(const float4*)src;
    ushort4 o;
    o.x = f2bf(v.x); o.y = f2bf(v.y); o.z = f2bf(v.z); o.w = f2bf(v.w);
    *(ushort4*)dst = o;
}

// ------- fused GEMM + LSTM: gates = Z @ V^T (+b), then elementwise cell ------
// 128x128 tile, BK=64, 4 waves (2x2) of 64x64, mfma_f32_16x16x32_bf16,
// global_load_lds width=16 staging, XOR-swizzled LDS (verified 0 conflicts).
// 16x16x32 (NOT 32x32x16): each 16-lane quarter reads a different col-block,
// so bank aliasing is 2-way max (free). 32x32 = structural 4-way (R2: +4cyc/read).
// XCD-aware block swizzle: each XCD gets an 8x16 (bx,by) rectangle -> 12 MB
// L2 working set instead of 18 MB.
__global__ __launch_bounds__(256, 4) void gemm_lstm(const unsigned short* __restrict__ Z,
                                                    const unsigned short* __restrict__ V,
                                                    const float* __restrict__ oc,
                                                    const float* __restrict__ bi,
                                                    const float* __restrict__ bo,
                                                    const float* __restrict__ bff,
                                                    const float* __restrict__ bc,
                                                    float* __restrict__ nh,
                                                    float* __restrict__ nc) {
    __shared__ float smem[8192];                 // 32 KB: lA+lB, reused by epilogue
    unsigned short* lA = (unsigned short*)smem;           // 16 KB
    unsigned short* lB = (unsigned short*)(smem + 4096);  // 16 KB

    const int tid  = threadIdx.x;
    const int lane = tid & 63;
    const int w    = tid >> 6;
    const int wr   = w >> 1;
    const int wc   = w & 1;

    // XCD swizzle (dispatch heuristic: block i -> XCD i&7)
    const int bid = blockIdx.x;
    const int xcd = bid & 7;
    const int j   = bid >> 3;                     // 0..127
    const int bx  = (xcd & 3) * 8 + (j & 7);      // 0..31
    const int by  = (xcd >> 2) * 16 + (j >> 3);   // 0..31
    const int m0  = by * 128;
    const int n0  = bx * 128;

    f32x4 acc[4][4];
#pragma unroll
    for (int i = 0; i < 4; ++i)
#pragma unroll
        for (int jj = 0; jj < 4; ++jj) acc[i][jj] = (f32x4){0.f, 0.f, 0.f, 0.f};

    // staging: 16 chunks of 1 KiB per tile; wave w owns chunks w*4 .. w*4+3.
    // XOR swizzle: col-block cb of row r lands at slot (cb ^ (r&7)).
    // global_load_lds dest = base + lane*16, so lane l (row lr=l>>3, dest
    // slot l&7) fetches global col-block (l&7) ^ lr.
    const int lr = lane >> 3;
    const int lc = ((lane & 7) ^ lr) * 8;
    const unsigned short* gA = Z + (size_t)(m0 + w * 32 + lr) * KD + lc;
    const unsigned short* gB = V + (size_t)(n0 + w * 32 + lr) * KD + lc;
    unsigned short* lAw = lA + w * 32 * 64;
    unsigned short* lBw = lB + w * 32 * 64;

    const int lm = lane & 15;

    for (int k0 = 0; k0 < KD; k0 += 64) {
#pragma unroll
        for (int c = 0; c < 4; ++c) {
            __builtin_amdgcn_global_load_lds(
                (const __attribute__((address_space(1))) void*)(gA + (size_t)c * 8 * KD + k0),
                (__attribute__((address_space(3))) void*)(lAw + c * 512), 16, 0, 0);
            __builtin_amdgcn_global_load_lds(
                (const __attribute__((address_space(1))) void*)(gB + (size_t)c * 8 * KD + k0),
                (__attribute__((address_space(3))) void*)(lBw + c * 512), 16, 0, 0);
        }
        __syncthreads();
#pragma unroll
        for (int ks = 0; ks < 2; ++ks) {
            bf16x8 af[4], bf[4];
            const int cb = ks * 4 + (lane >> 4);   // col-block 0..7 within row
            const int sw = (cb ^ (lm & 7)) * 8;    // swizzled short-offset
#pragma unroll
            for (int i = 0; i < 4; ++i) {
                af[i] = *(const bf16x8*)(lA + (wr * 64 + i * 16 + lm) * 64 + sw);
                bf[i] = *(const bf16x8*)(lB + (wc * 64 + i * 16 + lm) * 64 + sw);
            }
#pragma unroll
            for (int mi = 0; mi < 4; ++mi)
#pragma unroll
                for (int ni = 0; ni < 4; ++ni)
                    acc[mi][ni] = __builtin_amdgcn_mfma_f32_16x16x32_bf16(
                        af[mi], bf[ni], acc[mi][ni], 0, 0, 0);
        }
        __syncthreads();
    }

    // -------- fused LSTM epilogue (LDS-coalesced I/O) --------
    // acc element: row = m0+wr*64+mi*16+4a+v, col = n0+wc*64+ni*16+4b+g,
    // a=lane>>4, b=(lane>>2)&3, g=lane&3; col = 4*h + gate.
    // LDS scalar slot for (row_local, h_local): row*32 + (h ^ ((row&7)<<2))
    //   -> scalar scatter is 2-way banked (free), chunk-of-4 stays contiguous
    //   so float4 phases work on swizzled chunk bases.
    const int a  = lane >> 4;
    const int b  = (lane >> 2) & 3;
    const int g  = lane & 3;
    const int rowl0 = wr * 64 + 4 * a + g;   // + mi*16
    const int hl0   = wc * 16;               // + ni*4 + b
    const int h0g   = bx * 32;

    const int rr = tid >> 3;   // 0..31 (coalesced-phase row)
    const int cc = tid & 7;    // chunk 0..7

    // phase 0: coalesced old_c -> LDS (region smem[0..4096))
#pragma unroll
    for (int p = 0; p < 4; ++p) {
        const int row = p * 32 + rr;
        float4 v = *(const float4*)(oc + (size_t)(m0 + row) * H_ + h0g + 4 * cc);
        *(float4*)(smem + row * 32 + ((4 * cc) ^ ((row & 7) << 2))) = v;
    }
    __syncthreads();

    // phase 1: gather gates via XOR-shuffle, compute; keep results in regs
    float hv[4][4], cv[4][4];
#pragma unroll
    for (int ni = 0; ni < 4; ++ni) {
        const int hl = hl0 + ni * 4 + b;
        const int hg = h0g + hl;
        const float vbi = bi[hg];
        const float vbo = bo[hg];
        const float vbf = bff[hg];
        const float vbc = bc[hg];
#pragma unroll
        for (int mi = 0; mi < 4; ++mi) {
            const int rowl = rowl0 + mi * 16;
            const float ocv = smem[rowl * 32 + (hl ^ ((rowl & 7) << 2))];
            float recv[4];
#pragma unroll
            for (int t = 0; t < 4; ++t) {
                float x = acc[mi][ni][(g ^ t) & 3];
                recv[t] = __shfl_xor(x, t, 64);
            }
            float gi = recv[g] + vbi;
            float go = recv[g ^ 1] + vbo;
            float gf = recv[g ^ 2] + vbf;
            float gc = recv[g ^ 3] + vbc;
            float iv = 1.f / (1.f + __expf(-gi));
            float ov = 1.f / (1.f + __expf(-go));
            float fv = 1.f / (1.f + __expf(-gf));
            float ct = 1.f - 2.f / (__expf(2.f * gc) + 1.f);
            float c2 = fv * ocv + iv * ct;
            float th = 1.f - 2.f / (__expf(2.f * c2) + 1.f);
            cv[ni][mi] = c2;
            hv[ni][mi] = ov * th;
        }
    }
    __syncthreads();   // all old_c reads done before overwrite

    // phase 2: scatter results to LDS: nc -> smem[0..4096), nh -> smem[4096..)
#pragma unroll
    for (int ni = 0; ni < 4; ++ni)
#pragma unroll
        for (int mi = 0; mi < 4; ++mi) {
            const int rowl = rowl0 + mi * 16;
            const int hl = hl0 + ni * 4 + b;
            const int s = rowl * 32 + (hl ^ ((rowl & 7) << 2));
            smem[s] = cv[ni][mi];
            smem[4096 + s] = hv[ni][mi];
        }
    __syncthreads();

    // phase 3: coalesced global stores (128-B segments, 8 lanes per row)
#pragma unroll
    for (int p = 0; p < 4; ++p) {
        const int row = p * 32 + rr;
        const int s = row * 32 + ((4 * cc) ^ ((row & 7) << 2));
        float4 vcn = *(const float4*)(smem + s);
        float4 vhn = *(const float4*)(smem + 4096 + s);
        const size_t go = (size_t)(m0 + row) * H_ + h0g + 4 * cc;
        *(float4*)(nc + go) = vcn;
        *(float4*)(nh + go) = vhn;
    }
}

extern "C" void kernel_launch(void* const* d_in, const int* in_sizes, int n_in,
                              void* d_out, int out_size, void* d_ws, size_t ws_size,
                              hipStream_t stream) {
    const float* incoming = (const float*)d_in[0];
    const float* old_h    = (const float*)d_in[1];
    const float* old_c    = (const float*)d_in[2];
    const float* w_i = (const float*)d_in[3];
    const float* b_i = (const float*)d_in[4];
    const float* u_i = (const float*)d_in[5];
    const float* w_o = (const float*)d_in[6];
    const float* b_o = (const float*)d_in[7];
    const float* u_o = (const float*)d_in[8];
    const float* w_f = (const float*)d_in[9];
    const float* b_f = (const float*)d_in[10];
    const float* u_f = (const float*)d_in[11];
    const float* w_c = (const float*)d_in[12];
    const float* b_c = (const float*)d_in[13];
    const float* u_c = (const float*)d_in[14];

    unsigned short* Z = (unsigned short*)d_ws;                 // 16 MiB
    unsigned short* V = Z + (size_t)B_ * KD;                   // 16 MiB

    pack_all<<<16384, 256, 0, stream>>>(incoming, old_h,
                                        w_i, u_i, w_o, u_o, w_f, u_f, w_c, u_c,
                                        Z, V);
    gemm_lstm<<<1024, 256, 0, stream>>>(
        Z, V, old_c, b_i, b_o, b_f, b_c,
        (float*)d_out, (float*)d_out + (size_t)B_ * H_);
}

// Round 7
// 204.317 us; speedup vs baseline: 1.1737x; 1.0345x over previous
//
#include <hip/hip_runtime.h>

typedef __bf16 bf16x8 __attribute__((ext_vector_type(8)));
typedef float f32x4 __attribute__((ext_vector_type(4)));

#define B_  4096   // batch
#define IN_ 1024
#define H_  1024
#define KD  2048   // IN_ + H_
#define ND  4096   // 4 * H_ (gates interleaved: row n = 4*h + g)

__device__ __forceinline__ unsigned short f2bf(float f) {
    union { float f; unsigned u; } v; v.f = f;
    unsigned r = v.u + 0x7FFFu + ((v.u >> 16) & 1u);   // RNE
    return (unsigned short)(r >> 16);
}

// ------- pack Z = [incoming|old_h] -> bf16 [B_,KD]  and
//         pack V -> bf16 [ND,KD] with rows interleaved n = 4*h + g ------------
__global__ __launch_bounds__(256) void pack_all(const float* __restrict__ x,
                                                const float* __restrict__ h,
                                                const float* __restrict__ wi, const float* __restrict__ ui,
                                                const float* __restrict__ wo, const float* __restrict__ uo,
                                                const float* __restrict__ wf, const float* __restrict__ uf,
                                                const float* __restrict__ wc, const float* __restrict__ uc,
                                                unsigned short* __restrict__ Z,
                                                unsigned short* __restrict__ V) {
    const int bid = blockIdx.x;
    const float* src;
    unsigned short* dst;
    if (bid < 8192) {
        int idx = (bid * 256 + threadIdx.x) * 4;
        int m = idx >> 11;
        int k = idx & (KD - 1);
        src = (k < IN_) ? (x + (size_t)m * IN_ + k)
                        : (h + (size_t)m * H_ + (k - IN_));
        dst = Z + idx;
    } else {
        int idx = ((bid - 8192) * 256 + threadIdx.x) * 4;
        int n = idx >> 11;          // interleaved row
        int k = idx & (KD - 1);
        int g = n & 3;              // gate 0..3 = i,o,f,c
        int r = n >> 2;             // h index
        const float* wg = (g == 0) ? wi : (g == 1) ? wo : (g == 2) ? wf : wc;
        const float* ug = (g == 0) ? ui : (g == 1) ? uo : (g == 2) ? uf : uc;
        src = (k < IN_) ? (wg + (size_t)r * IN_ + k)
                        : (ug + (size_t)r * H_ + (k - IN_));
        dst = V + idx;
    }
    float4 v = *(const float4*)src;
    ushort4 o;
    o.x = f2bf(v.x); o.y = f2bf(v.y); o.z = f2bf(v.z); o.w = f2bf(v.w);
    *(ushort4*)dst = o;
}

// ------- fused GEMM + LSTM: gates = Z @ V^T (+b), then elementwise cell ------
// 128x128 tile, BK=64, 4 waves (2x2) of 64x64, mfma_f32_16x16x32_bf16,
// global_load_lds width=16 staging, XOR-swizzled LDS (verified 0 conflicts).
// 16x16x32 (NOT 32x32x16): each 16-lane quarter reads a different col-block,
// so bank aliasing is 2-way max (free). 32x32 = structural 4-way (R2: +4cyc/read).
// XCD-aware block swizzle: each XCD gets an 8x16 (bx,by) rectangle -> 12 MB
// L2 working set instead of 18 MB.
// __launch_bounds__(256,4) caps VGPR at 64 (R4: occupancy 20->33%).
__global__ __launch_bounds__(256, 4) void gemm_lstm(const unsigned short* __restrict__ Z,
                                                    const unsigned short* __restrict__ V,
                                                    const float* __restrict__ oc,
                                                    const float* __restrict__ bi,
                                                    const float* __restrict__ bo,
                                                    const float* __restrict__ bff,
                                                    const float* __restrict__ bc,
                                                    float* __restrict__ nh,
                                                    float* __restrict__ nc) {
    __shared__ float smem[8192];                 // 32 KB: lA+lB, reused by epilogue
    unsigned short* lA = (unsigned short*)smem;           // 16 KB
    unsigned short* lB = (unsigned short*)(smem + 4096);  // 16 KB

    const int tid  = threadIdx.x;
    const int lane = tid & 63;
    const int w    = tid >> 6;
    const int wr   = w >> 1;
    const int wc   = w & 1;

    // XCD swizzle (dispatch heuristic: block i -> XCD i&7)
    const int bid = blockIdx.x;
    const int xcd = bid & 7;
    const int j   = bid >> 3;                     // 0..127
    const int bx  = (xcd & 3) * 8 + (j & 7);      // 0..31
    const int by  = (xcd >> 2) * 16 + (j >> 3);   // 0..31
    const int m0  = by * 128;
    const int n0  = bx * 128;

    f32x4 acc[4][4];
#pragma unroll
    for (int i = 0; i < 4; ++i)
#pragma unroll
        for (int jj = 0; jj < 4; ++jj) acc[i][jj] = (f32x4){0.f, 0.f, 0.f, 0.f};

    // staging: 16 chunks of 1 KiB per tile; wave w owns chunks w*4 .. w*4+3.
    // XOR swizzle: col-block cb of row r lands at slot (cb ^ (r&7)).
    // global_load_lds dest = base + lane*16, so lane l (row lr=l>>3, dest
    // slot l&7) fetches global col-block (l&7) ^ lr.
    const int lr = lane >> 3;
    const int lc = ((lane & 7) ^ lr) * 8;
    const unsigned short* gA = Z + (size_t)(m0 + w * 32 + lr) * KD + lc;
    const unsigned short* gB = V + (size_t)(n0 + w * 32 + lr) * KD + lc;
    unsigned short* lAw = lA + w * 32 * 64;
    unsigned short* lBw = lB + w * 32 * 64;

    const int lm = lane & 15;

    for (int k0 = 0; k0 < KD; k0 += 64) {
#pragma unroll
        for (int c = 0; c < 4; ++c) {
            __builtin_amdgcn_global_load_lds(
                (const __attribute__((address_space(1))) void*)(gA + (size_t)c * 8 * KD + k0),
                (__attribute__((address_space(3))) void*)(lAw + c * 512), 16, 0, 0);
            __builtin_amdgcn_global_load_lds(
                (const __attribute__((address_space(1))) void*)(gB + (size_t)c * 8 * KD + k0),
                (__attribute__((address_space(3))) void*)(lBw + c * 512), 16, 0, 0);
        }
        __syncthreads();
#pragma unroll
        for (int ks = 0; ks < 2; ++ks) {
            bf16x8 af[4], bf[4];
            const int cb = ks * 4 + (lane >> 4);   // col-block 0..7 within row
            const int sw = (cb ^ (lm & 7)) * 8;    // swizzled short-offset
#pragma unroll
            for (int i = 0; i < 4; ++i) {
                af[i] = *(const bf16x8*)(lA + (wr * 64 + i * 16 + lm) * 64 + sw);
                bf[i] = *(const bf16x8*)(lB + (wc * 64 + i * 16 + lm) * 64 + sw);
            }
#pragma unroll
            for (int mi = 0; mi < 4; ++mi)
#pragma unroll
                for (int ni = 0; ni < 4; ++ni)
                    acc[mi][ni] = __builtin_amdgcn_mfma_f32_16x16x32_bf16(
                        af[mi], bf[ni], acc[mi][ni], 0, 0, 0);
        }
        __syncthreads();
    }

    // -------- fused LSTM epilogue (LDS-coalesced I/O) --------
    // acc element: row = m0+wr*64+mi*16+4a+v, col = n0+wc*64+ni*16+4b+g,
    // a=lane>>4, b=(lane>>2)&3, g=lane&3; col = 4*h + gate.
    // LDS scalar slot for (row_local, h_local): row*32 + (h ^ ((row&7)<<2))
    //   -> scalar scatter is 2-way banked (free), chunk-of-4 stays contiguous
    //   so float4 phases work on swizzled chunk bases.
    const int a  = lane >> 4;
    const int b  = (lane >> 2) & 3;
    const int g  = lane & 3;
    const int rowl0 = wr * 64 + 4 * a + g;   // + mi*16
    const int hl0   = wc * 16;               // + ni*4 + b
    const int h0g   = bx * 32;

    const int rr = tid >> 3;   // 0..31 (coalesced-phase row)
    const int cc = tid & 7;    // chunk 0..7

    // phase 0: coalesced old_c -> LDS (region smem[0..4096))
#pragma unroll
    for (int p = 0; p < 4; ++p) {
        const int row = p * 32 + rr;
        float4 v = *(const float4*)(oc + (size_t)(m0 + row) * H_ + h0g + 4 * cc);
        *(float4*)(smem + row * 32 + ((4 * cc) ^ ((row & 7) << 2))) = v;
    }
    __syncthreads();

    // phase 1: gather gates via XOR-shuffle, compute; keep results in regs
    float hv[4][4], cv[4][4];
#pragma unroll
    for (int ni = 0; ni < 4; ++ni) {
        const int hl = hl0 + ni * 4 + b;
        const int hg = h0g + hl;
        const float vbi = bi[hg];
        const float vbo = bo[hg];
        const float vbf = bff[hg];
        const float vbc = bc[hg];
#pragma unroll
        for (int mi = 0; mi < 4; ++mi) {
            const int rowl = rowl0 + mi * 16;
            const float ocv = smem[rowl * 32 + (hl ^ ((rowl & 7) << 2))];
            float recv[4];
#pragma unroll
            for (int t = 0; t < 4; ++t) {
                float xg = acc[mi][ni][(g ^ t) & 3];
                recv[t] = __shfl_xor(xg, t, 64);
            }
            float gi = recv[g] + vbi;
            float go = recv[g ^ 1] + vbo;
            float gf = recv[g ^ 2] + vbf;
            float gc = recv[g ^ 3] + vbc;
            float iv = 1.f / (1.f + __expf(-gi));
            float ov = 1.f / (1.f + __expf(-go));
            float fv = 1.f / (1.f + __expf(-gf));
            float ct = 1.f - 2.f / (__expf(2.f * gc) + 1.f);
            float c2 = fv * ocv + iv * ct;
            float th = 1.f - 2.f / (__expf(2.f * c2) + 1.f);
            cv[ni][mi] = c2;
            hv[ni][mi] = ov * th;
        }
    }
    __syncthreads();   // all old_c reads done before overwrite

    // phase 2: scatter results to LDS: nc -> smem[0..4096), nh -> smem[4096..)
#pragma unroll
    for (int ni = 0; ni < 4; ++ni)
#pragma unroll
        for (int mi = 0; mi < 4; ++mi) {
            const int rowl = rowl0 + mi * 16;
            const int hl = hl0 + ni * 4 + b;
            const int s = rowl * 32 + (hl ^ ((rowl & 7) << 2));
            smem[s] = cv[ni][mi];
            smem[4096 + s] = hv[ni][mi];
        }
    __syncthreads();

    // phase 3: coalesced global stores (128-B segments, 8 lanes per row)
#pragma unroll
    for (int p = 0; p < 4; ++p) {
        const int row = p * 32 + rr;
        const int s = row * 32 + ((4 * cc) ^ ((row & 7) << 2));
        float4 vcn = *(const float4*)(smem + s);
        float4 vhn = *(const float4*)(smem + 4096 + s);
        const size_t go = (size_t)(m0 + row) * H_ + h0g + 4 * cc;
        *(float4*)(nc + go) = vcn;
        *(float4*)(nh + go) = vhn;
    }
}

extern "C" void kernel_launch(void* const* d_in, const int* in_sizes, int n_in,
                              void* d_out, int out_size, void* d_ws, size_t ws_size,
                              hipStream_t stream) {
    const float* incoming = (const float*)d_in[0];
    const float* old_h    = (const float*)d_in[1];
    const float* old_c    = (const float*)d_in[2];
    const float* w_i = (const float*)d_in[3];
    const float* b_i = (const float*)d_in[4];
    const float* u_i = (const float*)d_in[5];
    const float* w_o = (const float*)d_in[6];
    const float* b_o = (const float*)d_in[7];
    const float* u_o = (const float*)d_in[8];
    const float* w_f = (const float*)d_in[9];
    const float* b_f = (const float*)d_in[10];
    const float* u_f = (const float*)d_in[11];
    const float* w_c = (const float*)d_in[12];
    const float* b_c = (const float*)d_in[13];
    const float* u_c = (const float*)d_in[14];

    unsigned short* Z = (unsigned short*)d_ws;                 // 16 MiB
    unsigned short* V = Z + (size_t)B_ * KD;                   // 16 MiB

    pack_all<<<16384, 256, 0, stream>>>(incoming, old_h,
                                        w_i, u_i, w_o, u_o, w_f, u_f, w_c, u_c,
                                        Z, V);
    gemm_lstm<<<1024, 256, 0, stream>>>(
        Z, V, old_c, b_i, b_o, b_f, b_c,
        (float*)d_out, (float*)d_out + (size_t)B_ * H_);
}